// Round 12
// baseline (166.329 us; speedup 1.0000x reference)
//
#include <hip/hip_runtime.h>
#include <hip/hip_bf16.h>

#define NN 100000
#define NE 800000
#define NG 2000
#define EMB 64
#define HID 128
#define NCLS 10

#define NBKT 196                       // coarse dst buckets (512 nodes each)
#define EPB 4096                       // edges per counting block
#define NBA ((NE + EPB - 1) / EPB)     // 196 counting blocks

typedef __attribute__((ext_vector_type(8))) short short8;
typedef __attribute__((ext_vector_type(4))) float f32x4;
typedef unsigned short u16;
typedef unsigned int u32;

// monotone float<->uint encoding so unsigned atomicMax == float max
static __device__ __forceinline__ unsigned fenc(float f) {
    unsigned u = __float_as_uint(f);
    return (u & 0x80000000u) ? ~u : (u | 0x80000000u);
}
static __device__ __forceinline__ float fdec(unsigned u) {
    return (u & 0x80000000u) ? __uint_as_float(u & 0x7FFFFFFFu) : __uint_as_float(~u);
}
static __device__ __forceinline__ u16 f2bf(float f) {
    u32 u = __float_as_uint(f);
    return (u16)((u + 0x7FFFu + ((u >> 16) & 1u)) >> 16);
}

// fused prologue: blocks [0,NBA) = coarse histogram; blocks [NBA,..) = embed + init
__global__ __launch_bounds__(256) void k_pre(
    const int* __restrict__ tok, const float* __restrict__ emb,
    const int* __restrict__ dst, int* __restrict__ counts,
    unsigned* __restrict__ genc, float* __restrict__ relp,
    u16* __restrict__ Bt1, u16* __restrict__ Bt2,
    const float* __restrict__ rel_table, const float* __restrict__ w1l,
    const float* __restrict__ w1r, const float* __restrict__ w2l,
    const float* __restrict__ w2r, u32* __restrict__ axw) {
    __shared__ int hist[NBKT];
    int g = blockIdx.x, t = threadIdx.x;
    if (g < NBA) {
        for (int i = t; i < NBKT; i += 256) hist[i] = 0;
        __syncthreads();
        int base = g * EPB;
        for (int j = t; j < EPB; j += 256) {
            int e = base + j;
            if (e < NE) atomicAdd(&hist[dst[e] >> 9], 1);
        }
        __syncthreads();
        for (int i = t; i < NBKT; i += 256)
            counts[i * NBA + g] = hist[i];  // bucket-major
        return;
    }
    int i = (g - NBA) * 256 + t;          // < NN*32 == 3.2M
    {   // embedding -> bf16 into x-half of ax[node][128]
        int n = i >> 5, p = i & 31;
        float2 e = *(const float2*)&emb[tok[n] * EMB + p * 2];
        axw[n * 64 + 32 + p] = (u32)f2bf(e.x) | ((u32)f2bf(e.y) << 16);
    }
    if (i < NG * HID) genc[i] = 0x007FFFFFu;  // fenc(-inf)
    if (i < 3 * HID) {
        int tt = i >> 7, j = i & 127;
        float s = 0.f;
        for (int k = 0; k < 16; ++k)
            s += rel_table[tt * 16 + k] * w1l[(64 + k) * HID + j];
        relp[i] = s;
    }
    if (i < 128 * 128) {
        int c = i >> 7, k = i & 127;
        float w = (k < 64) ? w1l[k * HID + c] : w1r[(k - 64) * HID + c];
        Bt1[c * 128 + k] = f2bf(w);
    }
    if (i < 128 * 256) {
        int c = i >> 8, k = i & 255;
        float w = (k < 128) ? w2l[k * HID + c] : w2r[(k - 128) * HID + c];
        Bt2[c * 256 + k] = f2bf(w);
    }
}

// scan A: per-bucket exclusive prefix over its NBA block-counts + bucket total
__global__ __launch_bounds__(256) void kS1(const int* __restrict__ counts,
                                           int* __restrict__ scanned,
                                           int* __restrict__ bucketT) {
    __shared__ int s[256];
    int b = blockIdx.x, t = threadIdx.x;
    int v = (t < NBA) ? counts[b * NBA + t] : 0;
    s[t] = v;
    __syncthreads();
    for (int off = 1; off < 256; off <<= 1) {
        int u = (t >= off) ? s[t - off] : 0;
        __syncthreads();
        s[t] += u;
        __syncthreads();
    }
    if (t < NBA) scanned[b * NBA + t] = s[t] - v;  // exclusive within bucket
    if (t == 255) bucketT[b] = s[255];
}

// pack: src(17) | etype(2)<<17 | dstlow(9)<<19. Inline bucket-base scan.
__global__ __launch_bounds__(256) void k_part(const int* __restrict__ src,
                                              const int* __restrict__ dst,
                                              const int* __restrict__ et,
                                              const int* __restrict__ scanned,
                                              const int* __restrict__ bucketT,
                                              u32* __restrict__ coarse) {
    __shared__ int cur[NBKT];
    __shared__ int s[256];
    int t = threadIdx.x;
    int v = (t < NBKT) ? bucketT[t] : 0;
    s[t] = v;
    __syncthreads();
    for (int off = 1; off < 256; off <<= 1) {
        int u = (t >= off) ? s[t - off] : 0;
        __syncthreads();
        s[t] += u;
        __syncthreads();
    }
    if (t < NBKT) cur[t] = (s[t] - v) + scanned[t * NBA + blockIdx.x];
    __syncthreads();
    int b0 = blockIdx.x * EPB;
    for (int j = t; j < EPB; j += 256) {
        int e = b0 + j;
        if (e < NE) {
            int d = dst[e];
            int pos = atomicAdd(&cur[d >> 9], 1);
            coarse[pos] = (u32)src[e] | ((u32)et[e] << 17) | ((u32)(d & 511) << 19);
        }
    }
}

__global__ __launch_bounds__(256) void k_csr(const int* __restrict__ bucketT,
                                             const u32* __restrict__ coarse,
                                             int* __restrict__ offsets,
                                             int* __restrict__ packed) {
    __shared__ int hist[512];
    __shared__ int ex[512];
    __shared__ int ts[256];
    __shared__ int sBeg, sEnd;
    int b = blockIdx.x, t = threadIdx.x;
    {   // inline bucket-base scan
        int v = (t < NBKT) ? bucketT[t] : 0;
        ts[t] = v;
        __syncthreads();
        for (int off = 1; off < 256; off <<= 1) {
            int u = (t >= off) ? ts[t - off] : 0;
            __syncthreads();
            ts[t] += u;
            __syncthreads();
        }
        if (t == b) { sBeg = ts[b] - v; sEnd = ts[b]; }
        __syncthreads();
    }
    int beg = sBeg, end = sEnd;
    hist[t] = 0; hist[t + 256] = 0;
    __syncthreads();
    for (int i = beg + t; i < end; i += 256)
        atomicAdd(&hist[(coarse[i] >> 19) & 511], 1);
    __syncthreads();
    int a0 = hist[2 * t], a1 = hist[2 * t + 1];
    int sum = a0 + a1;
    ts[t] = sum;
    __syncthreads();
    for (int off = 1; off < 256; off <<= 1) {
        int u = (t >= off) ? ts[t - off] : 0;
        __syncthreads();
        ts[t] += u;
        __syncthreads();
    }
    int ep = ts[t] - sum;
    ex[2 * t] = ep;
    ex[2 * t + 1] = ep + a0;
    __syncthreads();
    int node0 = b * 512;
    if (node0 + 2 * t < NN)     offsets[node0 + 2 * t]     = beg + ex[2 * t];
    if (node0 + 2 * t + 1 < NN) offsets[node0 + 2 * t + 1] = beg + ex[2 * t + 1];
    if (b == NBKT - 1 && t == 0) offsets[NN] = NE;
    hist[2 * t] = beg + ex[2 * t];
    hist[2 * t + 1] = beg + ex[2 * t + 1];
    __syncthreads();
    for (int i = beg + t; i < end; i += 256) {
        u32 pk = coarse[i];
        int pos = atomicAdd(&hist[(pk >> 19) & 511], 1);
        packed[pos] = (int)(pk & 0x1FFFFu) | (int)(((pk >> 17) & 3u) << 20);
    }
}

// gather1 (R9-stable numerics): mean of x[src] + type fractions into agg-half of ax.
// Half-wave split, scalar u32 loads.
__global__ __launch_bounds__(256) void k_agg1(
    const int* __restrict__ offsets, const int* __restrict__ packed,
    u32* __restrict__ axw, float* __restrict__ fc) {
    int node = (blockIdx.x * 256 + threadIdx.x) >> 6;
    int lane = threadIdx.x & 63;
    int half = lane >> 5;
    int fl = lane & 31;
    int beg = offsets[node], end = offsets[node + 1];
    float a0 = 0.f, a1 = 0.f;
    int c0 = 0, c1 = 0, c2 = 0;
    for (int cb = beg; cb < end; cb += 64) {
        int pk = packed[min(cb + lane, NE - 1)];
        int cnt = min(end - cb, 64);
        int j = 0;
        for (; j + 8 <= cnt; j += 8) {
            #pragma unroll
            for (int q = 0; q < 4; ++q) {
                int p = __shfl(pk, j + q * 2 + half, 64);
                u32 v = axw[(p & 0xFFFFF) * 64 + 32 + fl];
                a0 += __uint_as_float(v << 16);
                a1 += __uint_as_float(v & 0xFFFF0000u);
                int t = p >> 20;
                c0 += (t == 0); c1 += (t == 1); c2 += (t == 2);
            }
        }
        for (; j < cnt; j += 2) {
            int idx = j + half;
            if (idx < cnt) {
                int p = __shfl(pk, idx, 64);
                u32 v = axw[(p & 0xFFFFF) * 64 + 32 + fl];
                a0 += __uint_as_float(v << 16);
                a1 += __uint_as_float(v & 0xFFFF0000u);
                int t = p >> 20;
                c0 += (t == 0); c1 += (t == 1); c2 += (t == 2);
            }
        }
    }
    a0 += __shfl_xor(a0, 32, 64);
    a1 += __shfl_xor(a1, 32, 64);
    c0 += __shfl_xor(c0, 32, 64);
    c1 += __shfl_xor(c1, 32, 64);
    c2 += __shfl_xor(c2, 32, 64);
    float inv = 1.0f / (float)max(end - beg, 1);
    if (half == 0)
        axw[node * 64 + fl] = (u32)f2bf(a0 * inv) | ((u32)f2bf(a1 * inv) << 16);
    if (lane == 0)
        *(float4*)&fc[node * 4] = make_float4(c0 * inv, c1 * inv, c2 * inv, 0.f);
}

// gather2 (R9-stable numerics): mean of h[src] into agg-half of ah. Full-wave u32.
__global__ __launch_bounds__(256) void k_agg2(
    const int* __restrict__ offsets, const int* __restrict__ packed,
    u32* __restrict__ ahw) {
    int node = (blockIdx.x * 256 + threadIdx.x) >> 6;
    int lane = threadIdx.x & 63;
    int beg = offsets[node], end = offsets[node + 1];
    float a0 = 0.f, a1 = 0.f;
    for (int cb = beg; cb < end; cb += 64) {
        int pk = packed[min(cb + lane, NE - 1)] & 0xFFFFF;
        int cnt = min(end - cb, 64);
        int j = 0;
        for (; j + 4 <= cnt; j += 4) {
            int s0 = __shfl(pk, j, 64), s1 = __shfl(pk, j + 1, 64);
            int s2 = __shfl(pk, j + 2, 64), s3 = __shfl(pk, j + 3, 64);
            u32 u0 = ahw[(size_t)s0 * 128 + 64 + lane];
            u32 u1 = ahw[(size_t)s1 * 128 + 64 + lane];
            u32 u2 = ahw[(size_t)s2 * 128 + 64 + lane];
            u32 u3 = ahw[(size_t)s3 * 128 + 64 + lane];
            a0 += __uint_as_float(u0 << 16) + __uint_as_float(u1 << 16)
                + __uint_as_float(u2 << 16) + __uint_as_float(u3 << 16);
            a1 += __uint_as_float(u0 & 0xFFFF0000u) + __uint_as_float(u1 & 0xFFFF0000u)
                + __uint_as_float(u2 & 0xFFFF0000u) + __uint_as_float(u3 & 0xFFFF0000u);
        }
        for (; j < cnt; ++j) {
            u32 u = ahw[(size_t)__shfl(pk, j, 64) * 128 + 64 + lane];
            a0 += __uint_as_float(u << 16);
            a1 += __uint_as_float(u & 0xFFFF0000u);
        }
    }
    float inv = 1.0f / (float)max(end - beg, 1);
    ahw[node * 128 + lane] = (u32)f2bf(a0 * inv) | ((u32)f2bf(a1 * inv) << 16);
}

// MFMA GEMM layer1: M=128/block, 8 waves, wave tile 16x128, K=128.
__global__ __launch_bounds__(512) void k_gemm1(
    const u16* __restrict__ ax, const float* __restrict__ fc,
    const u16* __restrict__ Bt1, const float* __restrict__ b1,
    const float* __restrict__ relp, u16* __restrict__ ah) {
    __shared__ u16 Bs[128 * 128];   // 32KB; slot p holds chunk p^(col&7)
    int tid = threadIdx.x;
    int lane = tid & 63, w = tid >> 6;
    int mbase = blockIdx.x * 128;
    int r16 = lane & 15;
    int kg = (lane >> 4) * 8;
    int r = min(mbase + w * 16 + r16, NN - 1);
    short8 a[4];
    #pragma unroll
    for (int s = 0; s < 4; ++s)
        a[s] = *(const short8*)(ax + (size_t)r * 128 + s * 32 + kg);
    for (int i = tid; i < 2048; i += 512) {
        int col = i >> 4, p = i & 15;
        ((short8*)Bs)[i] = *(const short8*)(Bt1 + col * 128 + ((p ^ (col & 7)) << 3));
    }
    __syncthreads();
    f32x4 acc[8] = {};
    #pragma unroll
    for (int s = 0; s < 4; ++s) {
        int c = s * 4 + (lane >> 4);
        #pragma unroll
        for (int nf = 0; nf < 8; ++nf) {
            int col = nf * 16 + r16;
            short8 b = ((const short8*)Bs)[col * 16 + (c ^ (col & 7))];
            acc[nf] = __builtin_amdgcn_mfma_f32_16x16x32_bf16(a[s], b, acc[nf], 0, 0, 0);
        }
    }
    #pragma unroll
    for (int reg = 0; reg < 4; ++reg) {
        int row = mbase + w * 16 + (lane >> 4) * 4 + reg;
        if (row >= NN) continue;
        float4 f = *(const float4*)&fc[row * 4];
        #pragma unroll
        for (int nf = 0; nf < 8; ++nf) {
            int cc = nf * 16 + r16;
            float v = acc[nf][reg] + b1[cc]
                    + f.x * relp[cc] + f.y * relp[128 + cc] + f.z * relp[256 + cc];
            ah[(size_t)row * 256 + 128 + cc] = f2bf(fmaxf(v, 0.f));
        }
    }
}

// MFMA GEMM layer2: M=128/block, 8 waves, wave tile 16x128, K=256.
// Epilogue: wave-level segmented max (16 rows -> 1 atomic set when same graph).
__global__ __launch_bounds__(512) void k_gemm2(
    const u16* __restrict__ ah, const u16* __restrict__ Bt2,
    const float* __restrict__ b2, const int* __restrict__ batch,
    unsigned* __restrict__ genc) {
    __shared__ u16 Bs[128 * 256];   // 64KB; slot p holds chunk p^(col&7)
    int tid = threadIdx.x;
    int lane = tid & 63, w = tid >> 6;
    int mbase = blockIdx.x * 128;
    int r16 = lane & 15;
    int kg = (lane >> 4) * 8;
    int r = min(mbase + w * 16 + r16, NN - 1);
    short8 a[8];
    #pragma unroll
    for (int s = 0; s < 8; ++s)
        a[s] = *(const short8*)(ah + (size_t)r * 256 + s * 32 + kg);
    for (int i = tid; i < 4096; i += 512) {
        int col = i >> 5, p = i & 31;
        ((short8*)Bs)[i] = *(const short8*)(Bt2 + col * 256 + ((p ^ (col & 7)) << 3));
    }
    __syncthreads();
    f32x4 acc[8] = {};
    #pragma unroll
    for (int s = 0; s < 8; ++s) {
        int c = s * 4 + (lane >> 4);
        #pragma unroll
        for (int nf = 0; nf < 8; ++nf) {
            int col = nf * 16 + r16;
            short8 b = ((const short8*)Bs)[col * 32 + (c ^ (col & 7))];
            acc[nf] = __builtin_amdgcn_mfma_f32_16x16x32_bf16(a[s], b, acc[nf], 0, 0, 0);
        }
    }
    float bv[8];
    #pragma unroll
    for (int nf = 0; nf < 8; ++nf) bv[nf] = b2[nf * 16 + r16];
    int wbeg = mbase + w * 16;
    if (wbeg >= NN) return;
    int wlast = min(wbeg + 15, NN - 1);
    if (batch[wbeg] == batch[wlast]) {
        int bt = batch[wbeg];
        float vm[8];
        #pragma unroll
        for (int nf = 0; nf < 8; ++nf) {
            f32x4 v4 = acc[nf];
            vm[nf] = fmaxf(fmaxf(v4[0], v4[1]), fmaxf(v4[2], v4[3]));
        }
        #pragma unroll
        for (int nf = 0; nf < 8; ++nf)
            vm[nf] = fmaxf(vm[nf], __shfl_xor(vm[nf], 16, 64));
        #pragma unroll
        for (int nf = 0; nf < 8; ++nf)
            vm[nf] = fmaxf(vm[nf], __shfl_xor(vm[nf], 32, 64));
        if ((lane >> 4) == 0) {
            #pragma unroll
            for (int nf = 0; nf < 8; ++nf)
                atomicMax(&genc[bt * HID + nf * 16 + r16], fenc(vm[nf] + bv[nf]));
        }
    } else {
        int r0 = wbeg + (lane >> 4) * 4;
        if (r0 < NN) {
            if (r0 + 3 < NN && batch[r0] == batch[r0 + 3]) {
                int bt = batch[r0];
                #pragma unroll
                for (int nf = 0; nf < 8; ++nf) {
                    int cc = nf * 16 + r16;
                    f32x4 v4 = acc[nf];
                    float v = fmaxf(fmaxf(v4[0], v4[1]), fmaxf(v4[2], v4[3])) + bv[nf];
                    atomicMax(&genc[bt * HID + cc], fenc(v));
                }
            } else {
                #pragma unroll
                for (int reg = 0; reg < 4; ++reg) {
                    int row = r0 + reg;
                    if (row >= NN) continue;
                    int bt = batch[row];
                    #pragma unroll
                    for (int nf = 0; nf < 8; ++nf) {
                        int cc = nf * 16 + r16;
                        atomicMax(&genc[bt * HID + cc], fenc(acc[nf][reg] + bv[nf]));
                    }
                }
            }
        }
    }
}

__global__ void k_final(const unsigned* __restrict__ genc,
                        const float* __restrict__ lin_w, const float* __restrict__ lin_b,
                        float* __restrict__ out) {
    int gr = blockIdx.x;
    int lane = threadIdx.x;  // 64
    float g0 = fmaxf(fdec(genc[gr * HID + lane]), 0.f);
    float g1 = fmaxf(fdec(genc[gr * HID + 64 + lane]), 0.f);
    #pragma unroll
    for (int c = 0; c < NCLS; ++c) {
        float p = g0 * lin_w[lane * NCLS + c] + g1 * lin_w[(lane + 64) * NCLS + c];
        for (int off = 32; off > 0; off >>= 1)
            p += __shfl_down(p, off, 64);
        if (lane == 0) out[gr * NCLS + c] = p + lin_b[c];
    }
}

extern "C" void kernel_launch(void* const* d_in, const int* in_sizes, int n_in,
                              void* d_out, int out_size, void* d_ws, size_t ws_size,
                              hipStream_t stream) {
    const int* x_tokens   = (const int*)d_in[0];
    const int* edge_index = (const int*)d_in[1];
    const int* edge_type  = (const int*)d_in[2];
    const int* batch      = (const int*)d_in[3];
    const float* emb_table = (const float*)d_in[5];
    const float* rel_table = (const float*)d_in[6];
    const float* w1_l = (const float*)d_in[7];
    const float* b1   = (const float*)d_in[8];
    const float* w1_r = (const float*)d_in[9];
    const float* w2_l = (const float*)d_in[10];
    const float* b2   = (const float*)d_in[11];
    const float* w2_r = (const float*)d_in[12];
    const float* lin_w = (const float*)d_in[13];
    const float* lin_b = (const float*)d_in[14];
    float* out = (float*)d_out;

    const int* src = edge_index;
    const int* dst = edge_index + NE;

    char* ws = (char*)d_ws;
    size_t off = 0;
    auto alloc = [&](size_t bytes) {
        void* p = ws + off;
        off = (off + bytes + 255) & ~(size_t)255;
        return p;
    };
    u16* ax      = (u16*)alloc((size_t)NN * 128 * 2);    // 25.6 MB  [aggx | x]
    u16* ah      = (u16*)alloc((size_t)NN * 256 * 2);    // 51.2 MB  [aggh | h]
    float* fc    = (float*)alloc((size_t)NN * 4 * 4);
    int* offsets = (int*)alloc((size_t)(NN + 1) * 4);
    int* packed  = (int*)alloc((size_t)NE * 4);
    u32* coarse  = (u32*)alloc((size_t)NE * 4);
    int* counts  = (int*)alloc((size_t)NBKT * NBA * 4);
    int* scanned = (int*)alloc((size_t)NBKT * NBA * 4);
    int* bucketT = (int*)alloc((size_t)NBKT * 4);
    unsigned* genc = (unsigned*)alloc((size_t)NG * HID * 4);
    float* relp  = (float*)alloc((size_t)3 * HID * 4);
    u16* Bt1     = (u16*)alloc((size_t)128 * 128 * 2);
    u16* Bt2     = (u16*)alloc((size_t)128 * 256 * 2);
    (void)ws_size; (void)in_sizes; (void)n_in; (void)out_size;

    const int MT = (NN + 127) / 128;          // 782 GEMM m-tiles
    const int PRE = NBA + NN * 32 / 256;      // 196 + 12500

    hipLaunchKernelGGL(k_pre,   dim3(PRE), dim3(256), 0, stream,
                       x_tokens, emb_table, dst, counts, genc, relp, Bt1, Bt2,
                       rel_table, w1_l, w1_r, w2_l, w2_r, (u32*)ax);
    hipLaunchKernelGGL(kS1,     dim3(NBKT), dim3(256), 0, stream, counts, scanned, bucketT);
    hipLaunchKernelGGL(k_part,  dim3(NBA), dim3(256), 0, stream,
                       src, dst, edge_type, scanned, bucketT, coarse);
    hipLaunchKernelGGL(k_csr,   dim3(NBKT), dim3(256), 0, stream,
                       bucketT, coarse, offsets, packed);
    hipLaunchKernelGGL(k_agg1,  dim3(NN / 4), dim3(256), 0, stream,
                       offsets, packed, (u32*)ax, fc);
    hipLaunchKernelGGL(k_gemm1, dim3(MT), dim3(512), 0, stream,
                       ax, fc, Bt1, b1, relp, ah);
    hipLaunchKernelGGL(k_agg2,  dim3(NN / 4), dim3(256), 0, stream,
                       offsets, packed, (u32*)ah);
    hipLaunchKernelGGL(k_gemm2, dim3(MT), dim3(512), 0, stream,
                       ah, Bt2, b2, batch, genc);
    hipLaunchKernelGGL(k_final, dim3(NG), dim3(64), 0, stream, genc, lin_w, lin_b, out);
}

// Round 13
// 154.245 us; speedup vs baseline: 1.0783x; 1.0783x over previous
//
#include <hip/hip_runtime.h>
#include <hip/hip_bf16.h>

#define NN 100000
#define NE 800000
#define NG 2000
#define EMB 64
#define HID 128
#define NCLS 10

#define NBKT 196                       // coarse dst buckets (512 nodes each)
#define EPB 4096                       // edges per counting block
#define NBA ((NE + EPB - 1) / EPB)     // 196 counting blocks

typedef __attribute__((ext_vector_type(8))) short short8;
typedef __attribute__((ext_vector_type(4))) float f32x4;
typedef unsigned short u16;
typedef unsigned int u32;

// monotone float<->uint encoding so unsigned atomicMax == float max
static __device__ __forceinline__ unsigned fenc(float f) {
    unsigned u = __float_as_uint(f);
    return (u & 0x80000000u) ? ~u : (u | 0x80000000u);
}
static __device__ __forceinline__ float fdec(unsigned u) {
    return (u & 0x80000000u) ? __uint_as_float(u & 0x7FFFFFFFu) : __uint_as_float(~u);
}
static __device__ __forceinline__ u16 f2bf(float f) {
    u32 u = __float_as_uint(f);
    return (u16)((u + 0x7FFFu + ((u >> 16) & 1u)) >> 16);
}

// fused prologue: blocks [0,NBA) = coarse histogram; blocks [NBA,..) = embed + init
__global__ __launch_bounds__(256) void k_pre(
    const int* __restrict__ tok, const float* __restrict__ emb,
    const int* __restrict__ dst, int* __restrict__ counts,
    unsigned* __restrict__ genc, float* __restrict__ relp,
    u16* __restrict__ Bt1, u16* __restrict__ Bt2,
    const float* __restrict__ rel_table, const float* __restrict__ w1l,
    const float* __restrict__ w1r, const float* __restrict__ w2l,
    const float* __restrict__ w2r, u32* __restrict__ axw) {
    __shared__ int hist[NBKT];
    int g = blockIdx.x, t = threadIdx.x;
    if (g < NBA) {
        for (int i = t; i < NBKT; i += 256) hist[i] = 0;
        __syncthreads();
        int base = g * EPB;
        for (int j = t; j < EPB; j += 256) {
            int e = base + j;
            if (e < NE) atomicAdd(&hist[dst[e] >> 9], 1);
        }
        __syncthreads();
        for (int i = t; i < NBKT; i += 256)
            counts[i * NBA + g] = hist[i];  // bucket-major
        return;
    }
    int i = (g - NBA) * 256 + t;          // < NN*32 == 3.2M
    {   // embedding -> bf16 into x-half of ax[node][128]
        int n = i >> 5, p = i & 31;
        float2 e = *(const float2*)&emb[tok[n] * EMB + p * 2];
        axw[n * 64 + 32 + p] = (u32)f2bf(e.x) | ((u32)f2bf(e.y) << 16);
    }
    if (i < NG * HID) genc[i] = 0x007FFFFFu;  // fenc(-inf)
    if (i < 3 * HID) {
        int tt = i >> 7, j = i & 127;
        float s = 0.f;
        for (int k = 0; k < 16; ++k)
            s += rel_table[tt * 16 + k] * w1l[(64 + k) * HID + j];
        relp[i] = s;
    }
    if (i < 128 * 128) {
        int c = i >> 7, k = i & 127;
        float w = (k < 64) ? w1l[k * HID + c] : w1r[(k - 64) * HID + c];
        Bt1[c * 128 + k] = f2bf(w);
    }
    if (i < 128 * 256) {
        int c = i >> 8, k = i & 255;
        float w = (k < 128) ? w2l[k * HID + c] : w2r[(k - 128) * HID + c];
        Bt2[c * 256 + k] = f2bf(w);
    }
}

// scan A: per-bucket exclusive prefix over its NBA block-counts + bucket total
__global__ __launch_bounds__(256) void kS1(const int* __restrict__ counts,
                                           int* __restrict__ scanned,
                                           int* __restrict__ bucketT) {
    __shared__ int s[256];
    int b = blockIdx.x, t = threadIdx.x;
    int v = (t < NBA) ? counts[b * NBA + t] : 0;
    s[t] = v;
    __syncthreads();
    for (int off = 1; off < 256; off <<= 1) {
        int u = (t >= off) ? s[t - off] : 0;
        __syncthreads();
        s[t] += u;
        __syncthreads();
    }
    if (t < NBA) scanned[b * NBA + t] = s[t] - v;  // exclusive within bucket
    if (t == 255) bucketT[b] = s[255];
}

// pack: src(17) | etype(2)<<17 | dstlow(9)<<19. Inline bucket-base scan.
__global__ __launch_bounds__(256) void k_part(const int* __restrict__ src,
                                              const int* __restrict__ dst,
                                              const int* __restrict__ et,
                                              const int* __restrict__ scanned,
                                              const int* __restrict__ bucketT,
                                              u32* __restrict__ coarse) {
    __shared__ int cur[NBKT];
    __shared__ int s[256];
    int t = threadIdx.x;
    int v = (t < NBKT) ? bucketT[t] : 0;
    s[t] = v;
    __syncthreads();
    for (int off = 1; off < 256; off <<= 1) {
        int u = (t >= off) ? s[t - off] : 0;
        __syncthreads();
        s[t] += u;
        __syncthreads();
    }
    if (t < NBKT) cur[t] = (s[t] - v) + scanned[t * NBA + blockIdx.x];
    __syncthreads();
    int b0 = blockIdx.x * EPB;
    for (int j = t; j < EPB; j += 256) {
        int e = b0 + j;
        if (e < NE) {
            int d = dst[e];
            int pos = atomicAdd(&cur[d >> 9], 1);
            coarse[pos] = (u32)src[e] | ((u32)et[e] << 17) | ((u32)(d & 511) << 19);
        }
    }
}

__global__ __launch_bounds__(256) void k_csr(const int* __restrict__ bucketT,
                                             const u32* __restrict__ coarse,
                                             int* __restrict__ offsets,
                                             int* __restrict__ packed) {
    __shared__ int hist[512];
    __shared__ int ex[512];
    __shared__ int ts[256];
    __shared__ int sBeg, sEnd;
    int b = blockIdx.x, t = threadIdx.x;
    {   // inline bucket-base scan
        int v = (t < NBKT) ? bucketT[t] : 0;
        ts[t] = v;
        __syncthreads();
        for (int off = 1; off < 256; off <<= 1) {
            int u = (t >= off) ? ts[t - off] : 0;
            __syncthreads();
            ts[t] += u;
            __syncthreads();
        }
        if (t == b) { sBeg = ts[b] - v; sEnd = ts[b]; }
        __syncthreads();
    }
    int beg = sBeg, end = sEnd;
    hist[t] = 0; hist[t + 256] = 0;
    __syncthreads();
    for (int i = beg + t; i < end; i += 256)
        atomicAdd(&hist[(coarse[i] >> 19) & 511], 1);
    __syncthreads();
    int a0 = hist[2 * t], a1 = hist[2 * t + 1];
    int sum = a0 + a1;
    ts[t] = sum;
    __syncthreads();
    for (int off = 1; off < 256; off <<= 1) {
        int u = (t >= off) ? ts[t - off] : 0;
        __syncthreads();
        ts[t] += u;
        __syncthreads();
    }
    int ep = ts[t] - sum;
    ex[2 * t] = ep;
    ex[2 * t + 1] = ep + a0;
    __syncthreads();
    int node0 = b * 512;
    if (node0 + 2 * t < NN)     offsets[node0 + 2 * t]     = beg + ex[2 * t];
    if (node0 + 2 * t + 1 < NN) offsets[node0 + 2 * t + 1] = beg + ex[2 * t + 1];
    if (b == NBKT - 1 && t == 0) offsets[NN] = NE;
    hist[2 * t] = beg + ex[2 * t];
    hist[2 * t + 1] = beg + ex[2 * t + 1];
    __syncthreads();
    for (int i = beg + t; i < end; i += 256) {
        u32 pk = coarse[i];
        int pos = atomicAdd(&hist[(pk >> 19) & 511], 1);
        packed[pos] = (int)(pk & 0x1FFFFu) | (int)(((pk >> 17) & 3u) << 20);
    }
}

// gather1: 2 nodes per wave (32-lane groups). Within a group: 16-lane even/odd
// edge sub-split, uint2 loads (4 feats/lane). Per-feature summation sequence is
// bit-identical to the R12 half-wave scalar version (same edge order, same
// even-partial + odd-partial association).
__global__ __launch_bounds__(256) void k_agg1(
    const int* __restrict__ offsets, const int* __restrict__ packed,
    u32* __restrict__ axw, float* __restrict__ fc) {
    int node = (blockIdx.x * 256 + threadIdx.x) >> 5;   // 8 nodes per block
    int gl = threadIdx.x & 31;       // lane within node group
    int sub = gl >> 4;               // 0 = even edges, 1 = odd edges
    int sl = gl & 15;                // feature lane (uint2 -> u32 pair 2sl,2sl+1)
    int beg = offsets[node], end = offsets[node + 1];
    float a0 = 0.f, a1 = 0.f, a2 = 0.f, a3 = 0.f;
    int c0 = 0, c1 = 0, c2 = 0;
    for (int cb = beg; cb < end; cb += 32) {
        int pk = packed[min(cb + gl, NE - 1)];
        int cnt = min(end - cb, 32);
        int j = 0;
        for (; j + 8 <= cnt; j += 8) {
            #pragma unroll
            for (int q = 0; q < 4; ++q) {
                int p = __shfl(pk, j + q * 2 + sub, 32);
                uint2 v = *(const uint2*)&axw[(p & 0xFFFFF) * 64 + 32 + 2 * sl];
                a0 += __uint_as_float(v.x << 16);
                a1 += __uint_as_float(v.x & 0xFFFF0000u);
                a2 += __uint_as_float(v.y << 16);
                a3 += __uint_as_float(v.y & 0xFFFF0000u);
                int t = p >> 20;
                c0 += (t == 0); c1 += (t == 1); c2 += (t == 2);
            }
        }
        for (; j < cnt; j += 2) {
            int idx = j + sub;
            if (idx < cnt) {
                int p = __shfl(pk, idx, 32);
                uint2 v = *(const uint2*)&axw[(p & 0xFFFFF) * 64 + 32 + 2 * sl];
                a0 += __uint_as_float(v.x << 16);
                a1 += __uint_as_float(v.x & 0xFFFF0000u);
                a2 += __uint_as_float(v.y << 16);
                a3 += __uint_as_float(v.y & 0xFFFF0000u);
                int t = p >> 20;
                c0 += (t == 0); c1 += (t == 1); c2 += (t == 2);
            }
        }
    }
    // merge even + odd partials within the 32-lane group
    a0 += __shfl_xor(a0, 16, 32);
    a1 += __shfl_xor(a1, 16, 32);
    a2 += __shfl_xor(a2, 16, 32);
    a3 += __shfl_xor(a3, 16, 32);
    c0 += __shfl_xor(c0, 16, 32);
    c1 += __shfl_xor(c1, 16, 32);
    c2 += __shfl_xor(c2, 16, 32);
    float inv = 1.0f / (float)max(end - beg, 1);
    if (sub == 0) {
        uint2 o;
        o.x = (u32)f2bf(a0 * inv) | ((u32)f2bf(a1 * inv) << 16);
        o.y = (u32)f2bf(a2 * inv) | ((u32)f2bf(a3 * inv) << 16);
        *(uint2*)&axw[node * 64 + 2 * sl] = o;
    }
    if (gl == 0)
        *(float4*)&fc[node * 4] = make_float4(c0 * inv, c1 * inv, c2 * inv, 0.f);
}

// gather2: 2 nodes per wave (32-lane groups), uint2 loads (4 feats/lane),
// sequential edge order with the same 4-edge grouping as R12 -> bit-identical sums.
__global__ __launch_bounds__(256) void k_agg2(
    const int* __restrict__ offsets, const int* __restrict__ packed,
    u32* __restrict__ ahw) {
    int node = (blockIdx.x * 256 + threadIdx.x) >> 5;   // 8 nodes per block
    int gl = threadIdx.x & 31;
    int beg = offsets[node], end = offsets[node + 1];
    float a0 = 0.f, a1 = 0.f, a2 = 0.f, a3 = 0.f;
    for (int cb = beg; cb < end; cb += 32) {
        int pk = packed[min(cb + gl, NE - 1)] & 0xFFFFF;
        int cnt = min(end - cb, 32);
        int j = 0;
        for (; j + 4 <= cnt; j += 4) {
            int s0 = __shfl(pk, j, 32), s1 = __shfl(pk, j + 1, 32);
            int s2 = __shfl(pk, j + 2, 32), s3 = __shfl(pk, j + 3, 32);
            uint2 v0 = *(const uint2*)&ahw[(size_t)s0 * 128 + 64 + 2 * gl];
            uint2 v1 = *(const uint2*)&ahw[(size_t)s1 * 128 + 64 + 2 * gl];
            uint2 v2 = *(const uint2*)&ahw[(size_t)s2 * 128 + 64 + 2 * gl];
            uint2 v3 = *(const uint2*)&ahw[(size_t)s3 * 128 + 64 + 2 * gl];
            a0 += __uint_as_float(v0.x << 16) + __uint_as_float(v1.x << 16)
                + __uint_as_float(v2.x << 16) + __uint_as_float(v3.x << 16);
            a1 += __uint_as_float(v0.x & 0xFFFF0000u) + __uint_as_float(v1.x & 0xFFFF0000u)
                + __uint_as_float(v2.x & 0xFFFF0000u) + __uint_as_float(v3.x & 0xFFFF0000u);
            a2 += __uint_as_float(v0.y << 16) + __uint_as_float(v1.y << 16)
                + __uint_as_float(v2.y << 16) + __uint_as_float(v3.y << 16);
            a3 += __uint_as_float(v0.y & 0xFFFF0000u) + __uint_as_float(v1.y & 0xFFFF0000u)
                + __uint_as_float(v2.y & 0xFFFF0000u) + __uint_as_float(v3.y & 0xFFFF0000u);
        }
        for (; j < cnt; ++j) {
            int p = __shfl(pk, j, 32);
            uint2 v = *(const uint2*)&ahw[(size_t)p * 128 + 64 + 2 * gl];
            a0 += __uint_as_float(v.x << 16);
            a1 += __uint_as_float(v.x & 0xFFFF0000u);
            a2 += __uint_as_float(v.y << 16);
            a3 += __uint_as_float(v.y & 0xFFFF0000u);
        }
    }
    float inv = 1.0f / (float)max(end - beg, 1);
    uint2 o;
    o.x = (u32)f2bf(a0 * inv) | ((u32)f2bf(a1 * inv) << 16);
    o.y = (u32)f2bf(a2 * inv) | ((u32)f2bf(a3 * inv) << 16);
    *(uint2*)&ahw[node * 128 + 2 * gl] = o;
}

// MFMA GEMM layer1: M=128/block, 8 waves, wave tile 16x128, K=128.
__global__ __launch_bounds__(512) void k_gemm1(
    const u16* __restrict__ ax, const float* __restrict__ fc,
    const u16* __restrict__ Bt1, const float* __restrict__ b1,
    const float* __restrict__ relp, u16* __restrict__ ah) {
    __shared__ u16 Bs[128 * 128];   // 32KB; slot p holds chunk p^(col&7)
    int tid = threadIdx.x;
    int lane = tid & 63, w = tid >> 6;
    int mbase = blockIdx.x * 128;
    int r16 = lane & 15;
    int kg = (lane >> 4) * 8;
    int r = min(mbase + w * 16 + r16, NN - 1);
    short8 a[4];
    #pragma unroll
    for (int s = 0; s < 4; ++s)
        a[s] = *(const short8*)(ax + (size_t)r * 128 + s * 32 + kg);
    for (int i = tid; i < 2048; i += 512) {
        int col = i >> 4, p = i & 15;
        ((short8*)Bs)[i] = *(const short8*)(Bt1 + col * 128 + ((p ^ (col & 7)) << 3));
    }
    __syncthreads();
    f32x4 acc[8] = {};
    #pragma unroll
    for (int s = 0; s < 4; ++s) {
        int c = s * 4 + (lane >> 4);
        #pragma unroll
        for (int nf = 0; nf < 8; ++nf) {
            int col = nf * 16 + r16;
            short8 b = ((const short8*)Bs)[col * 16 + (c ^ (col & 7))];
            acc[nf] = __builtin_amdgcn_mfma_f32_16x16x32_bf16(a[s], b, acc[nf], 0, 0, 0);
        }
    }
    #pragma unroll
    for (int reg = 0; reg < 4; ++reg) {
        int row = mbase + w * 16 + (lane >> 4) * 4 + reg;
        if (row >= NN) continue;
        float4 f = *(const float4*)&fc[row * 4];
        #pragma unroll
        for (int nf = 0; nf < 8; ++nf) {
            int cc = nf * 16 + r16;
            float v = acc[nf][reg] + b1[cc]
                    + f.x * relp[cc] + f.y * relp[128 + cc] + f.z * relp[256 + cc];
            ah[(size_t)row * 256 + 128 + cc] = f2bf(fmaxf(v, 0.f));
        }
    }
}

// MFMA GEMM layer2: M=128/block, 8 waves, wave tile 16x128, K=256.
// Two-phase B staging (32KB LDS -> higher occupancy). MFMA order s=0..7 unchanged.
__global__ __launch_bounds__(512) void k_gemm2(
    const u16* __restrict__ ah, const u16* __restrict__ Bt2,
    const float* __restrict__ b2, const int* __restrict__ batch,
    unsigned* __restrict__ genc) {
    __shared__ u16 Bs[128 * 128];   // 32KB per phase; slot p holds chunk p^(col&7)
    int tid = threadIdx.x;
    int lane = tid & 63, w = tid >> 6;
    int mbase = blockIdx.x * 128;
    int r16 = lane & 15;
    int kg = (lane >> 4) * 8;
    int r = min(mbase + w * 16 + r16, NN - 1);
    short8 a[8];
    #pragma unroll
    for (int s = 0; s < 8; ++s)
        a[s] = *(const short8*)(ah + (size_t)r * 256 + s * 32 + kg);
    // phase 0: K 0..127
    for (int i = tid; i < 2048; i += 512) {
        int col = i >> 4, p = i & 15;
        ((short8*)Bs)[i] = *(const short8*)(Bt2 + col * 256 + ((p ^ (col & 7)) << 3));
    }
    __syncthreads();
    f32x4 acc[8] = {};
    #pragma unroll
    for (int s = 0; s < 4; ++s) {
        int c = s * 4 + (lane >> 4);
        #pragma unroll
        for (int nf = 0; nf < 8; ++nf) {
            int col = nf * 16 + r16;
            short8 b = ((const short8*)Bs)[col * 16 + (c ^ (col & 7))];
            acc[nf] = __builtin_amdgcn_mfma_f32_16x16x32_bf16(a[s], b, acc[nf], 0, 0, 0);
        }
    }
    __syncthreads();
    // phase 1: K 128..255
    for (int i = tid; i < 2048; i += 512) {
        int col = i >> 4, p = i & 15;
        ((short8*)Bs)[i] = *(const short8*)(Bt2 + col * 256 + 128 + ((p ^ (col & 7)) << 3));
    }
    __syncthreads();
    #pragma unroll
    for (int s = 4; s < 8; ++s) {
        int c = (s - 4) * 4 + (lane >> 4);
        #pragma unroll
        for (int nf = 0; nf < 8; ++nf) {
            int col = nf * 16 + r16;
            short8 b = ((const short8*)Bs)[col * 16 + (c ^ (col & 7))];
            acc[nf] = __builtin_amdgcn_mfma_f32_16x16x32_bf16(a[s], b, acc[nf], 0, 0, 0);
        }
    }
    float bv[8];
    #pragma unroll
    for (int nf = 0; nf < 8; ++nf) bv[nf] = b2[nf * 16 + r16];
    int wbeg = mbase + w * 16;
    if (wbeg >= NN) return;
    int wlast = min(wbeg + 15, NN - 1);
    if (batch[wbeg] == batch[wlast]) {
        int bt = batch[wbeg];
        float vm[8];
        #pragma unroll
        for (int nf = 0; nf < 8; ++nf) {
            f32x4 v4 = acc[nf];
            vm[nf] = fmaxf(fmaxf(v4[0], v4[1]), fmaxf(v4[2], v4[3]));
        }
        #pragma unroll
        for (int nf = 0; nf < 8; ++nf)
            vm[nf] = fmaxf(vm[nf], __shfl_xor(vm[nf], 16, 64));
        #pragma unroll
        for (int nf = 0; nf < 8; ++nf)
            vm[nf] = fmaxf(vm[nf], __shfl_xor(vm[nf], 32, 64));
        if ((lane >> 4) == 0) {
            #pragma unroll
            for (int nf = 0; nf < 8; ++nf)
                atomicMax(&genc[bt * HID + nf * 16 + r16], fenc(vm[nf] + bv[nf]));
        }
    } else {
        int r0 = wbeg + (lane >> 4) * 4;
        if (r0 < NN) {
            if (r0 + 3 < NN && batch[r0] == batch[r0 + 3]) {
                int bt = batch[r0];
                #pragma unroll
                for (int nf = 0; nf < 8; ++nf) {
                    int cc = nf * 16 + r16;
                    f32x4 v4 = acc[nf];
                    float v = fmaxf(fmaxf(v4[0], v4[1]), fmaxf(v4[2], v4[3])) + bv[nf];
                    atomicMax(&genc[bt * HID + cc], fenc(v));
                }
            } else {
                #pragma unroll
                for (int reg = 0; reg < 4; ++reg) {
                    int row = r0 + reg;
                    if (row >= NN) continue;
                    int bt = batch[row];
                    #pragma unroll
                    for (int nf = 0; nf < 8; ++nf) {
                        int cc = nf * 16 + r16;
                        atomicMax(&genc[bt * HID + cc], fenc(acc[nf][reg] + bv[nf]));
                    }
                }
            }
        }
    }
}

__global__ void k_final(const unsigned* __restrict__ genc,
                        const float* __restrict__ lin_w, const float* __restrict__ lin_b,
                        float* __restrict__ out) {
    int gr = blockIdx.x;
    int lane = threadIdx.x;  // 64
    float g0 = fmaxf(fdec(genc[gr * HID + lane]), 0.f);
    float g1 = fmaxf(fdec(genc[gr * HID + 64 + lane]), 0.f);
    #pragma unroll
    for (int c = 0; c < NCLS; ++c) {
        float p = g0 * lin_w[lane * NCLS + c] + g1 * lin_w[(lane + 64) * NCLS + c];
        for (int off = 32; off > 0; off >>= 1)
            p += __shfl_down(p, off, 64);
        if (lane == 0) out[gr * NCLS + c] = p + lin_b[c];
    }
}

extern "C" void kernel_launch(void* const* d_in, const int* in_sizes, int n_in,
                              void* d_out, int out_size, void* d_ws, size_t ws_size,
                              hipStream_t stream) {
    const int* x_tokens   = (const int*)d_in[0];
    const int* edge_index = (const int*)d_in[1];
    const int* edge_type  = (const int*)d_in[2];
    const int* batch      = (const int*)d_in[3];
    const float* emb_table = (const float*)d_in[5];
    const float* rel_table = (const float*)d_in[6];
    const float* w1_l = (const float*)d_in[7];
    const float* b1   = (const float*)d_in[8];
    const float* w1_r = (const float*)d_in[9];
    const float* w2_l = (const float*)d_in[10];
    const float* b2   = (const float*)d_in[11];
    const float* w2_r = (const float*)d_in[12];
    const float* lin_w = (const float*)d_in[13];
    const float* lin_b = (const float*)d_in[14];
    float* out = (float*)d_out;

    const int* src = edge_index;
    const int* dst = edge_index + NE;

    char* ws = (char*)d_ws;
    size_t off = 0;
    auto alloc = [&](size_t bytes) {
        void* p = ws + off;
        off = (off + bytes + 255) & ~(size_t)255;
        return p;
    };
    u16* ax      = (u16*)alloc((size_t)NN * 128 * 2);    // 25.6 MB  [aggx | x]
    u16* ah      = (u16*)alloc((size_t)NN * 256 * 2);    // 51.2 MB  [aggh | h]
    float* fc    = (float*)alloc((size_t)NN * 4 * 4);
    int* offsets = (int*)alloc((size_t)(NN + 1) * 4);
    int* packed  = (int*)alloc((size_t)NE * 4);
    u32* coarse  = (u32*)alloc((size_t)NE * 4);
    int* counts  = (int*)alloc((size_t)NBKT * NBA * 4);
    int* scanned = (int*)alloc((size_t)NBKT * NBA * 4);
    int* bucketT = (int*)alloc((size_t)NBKT * 4);
    unsigned* genc = (unsigned*)alloc((size_t)NG * HID * 4);
    float* relp  = (float*)alloc((size_t)3 * HID * 4);
    u16* Bt1     = (u16*)alloc((size_t)128 * 128 * 2);
    u16* Bt2     = (u16*)alloc((size_t)128 * 256 * 2);
    (void)ws_size; (void)in_sizes; (void)n_in; (void)out_size;

    const int MT = (NN + 127) / 128;          // 782 GEMM m-tiles
    const int PRE = NBA + NN * 32 / 256;      // 196 + 12500
    const int AGG = NN / 8;                   // 12500 (8 nodes per 256-thr block)

    hipLaunchKernelGGL(k_pre,   dim3(PRE), dim3(256), 0, stream,
                       x_tokens, emb_table, dst, counts, genc, relp, Bt1, Bt2,
                       rel_table, w1_l, w1_r, w2_l, w2_r, (u32*)ax);
    hipLaunchKernelGGL(kS1,     dim3(NBKT), dim3(256), 0, stream, counts, scanned, bucketT);
    hipLaunchKernelGGL(k_part,  dim3(NBA), dim3(256), 0, stream,
                       src, dst, edge_type, scanned, bucketT, coarse);
    hipLaunchKernelGGL(k_csr,   dim3(NBKT), dim3(256), 0, stream,
                       bucketT, coarse, offsets, packed);
    hipLaunchKernelGGL(k_agg1,  dim3(AGG), dim3(256), 0, stream,
                       offsets, packed, (u32*)ax, fc);
    hipLaunchKernelGGL(k_gemm1, dim3(MT), dim3(512), 0, stream,
                       ax, fc, Bt1, b1, relp, ah);
    hipLaunchKernelGGL(k_agg2,  dim3(AGG), dim3(256), 0, stream,
                       offsets, packed, (u32*)ah);
    hipLaunchKernelGGL(k_gemm2, dim3(MT), dim3(512), 0, stream,
                       ah, Bt2, b2, batch, genc);
    hipLaunchKernelGGL(k_final, dim3(NG), dim3(64), 0, stream, genc, lin_w, lin_b, out);
}